// Round 18
// baseline (151.332 us; speedup 1.0000x reference)
//
#include <hip/hip_runtime.h>
#include <math.h>

// ---------------------------------------------------------------------------
// EqMotion fused implementation. Pair passes on MFMA (fp16, swapped operands,
// in-register layer transitions), rest fp32 VALU.
// B=4, N=256, T_IN=10, T_OUT=20, HID=64, HALF=32, HC=64, NCAT=4.
// Outputs: x_out [4,256,20,3] (61440 f32) then category [4,256,256,4].
// coordT: channel-PAIR-packed fp16, [b][p*3+d][j] uint (= ch 2p, 2p+1).
// R15 lesson: sched_barrier(0) stage fences in k_pair are LOAD-BEARING.
// R16 lesson: no serial single-thread tails with global loads.
// R18: L2 fence window widened (Q2[16], 1 fence) — R7's half-split was a
// pressure fix; 60 VGPR leaves headroom under the 128 cap.
// ---------------------------------------------------------------------------

constexpr int WS_XC     = 0;                       // [4][3] stride 4
constexpr int WS_XMEAN  = 16;                      // [4][3] stride 4
constexpr int WS_XM2    = 32;                      // [4][3] stride 4
constexpr int WS_CTH    = 64;                      // [4][192][256] uint (fp16 pairs)
constexpr int WS_XH     = WS_CTH + 4*192*256;      // [4][256][64][3] f32
constexpr int WS_HH     = WS_XH + 4*256*64*3;      // [4][256][64]
constexpr int WS_BIASE  = WS_HH + 4*256*64;        // [4][256][64]
constexpr int WS_CONTRE = WS_BIASE + 4*256*64;     // [4][256][64]  (natural [n][o])
constexpr int WS_AGG    = WS_CONTRE + 4*256*64;    // [4][256][64]
constexpr int WS_BIASK  = WS_AGG + 4*256*64;       // [4][256][64]
constexpr int WS_CONTRK = WS_BIASK + 4*256*64;     // [4][256][64]  (natural [n][o])
constexpr int WS_WF     = WS_CONTRK + 4*256*64;    // 37888 ushorts (fragment-major f16 weights)

// fragment-major weight regions, in ushort units within WS_WF
constexpr int OW1  = 0;      // Wc1 as A [o][c]     64x128 -> 8192
constexpr int OW2  = 8192;   // Wc2 as A [cc][o]   128x64  -> 8192
constexpr int OWAE = 16384;  // We1[128:256] as A [o][cd]  -> 8192
constexpr int OWAK = 24576;  // Wk1[128:256] as A [o][cd]  -> 8192
constexpr int OWBE = 32768;  // We2 as A [o2][o]    64x64  -> 4096
constexpr int OWBK = 36864;  // Wk2 as A [cat][o] (pad16)  -> 1024
constexpr int WF_TOTAL = 37888;

#define PI_F 3.14159265358979323846f
#define EPS_F 1e-6f

typedef _Float16 f16x8 __attribute__((ext_vector_type(8)));
typedef _Float16 f16x2 __attribute__((ext_vector_type(2)));
typedef float f32x4 __attribute__((ext_vector_type(4)));

__device__ __forceinline__ float silu(float v) {
    float t = 1.0f + __expf(-v);
    return v * __builtin_amdgcn_rcpf(t);
}

__device__ __forceinline__ unsigned pk2(float a, float b) {
    union { _Float16 h[2]; unsigned u; } x;
    x.h[0] = (_Float16)a; x.h[1] = (_Float16)b;
    return x.u;
}

// layer transition: Q[ns][q] packed fp16 pairs (ns = 2*KT tiles, q=0/1) ->
// B-fragments for next MFMA. Per-lane mapping (derivation verified):
// slot (kt, v) <- lane 32*(lg&1) + 16*(v>=4) + lr, reg Q[2kt+(lg>>1)][(v&3)>>1].
template<int KT>
__device__ __forceinline__ void xfrag(const unsigned* Q, int S0, int S1, bool hi,
                                      f16x8* bf) {
#pragma unroll
    for (int kt = 0; kt < KT; ++kt) {
        unsigned a0 = (unsigned)__shfl((int)Q[(2 * kt) * 2 + 0], S0, 64);
        unsigned b0 = (unsigned)__shfl((int)Q[(2 * kt + 1) * 2 + 0], S0, 64);
        unsigned a1 = (unsigned)__shfl((int)Q[(2 * kt) * 2 + 1], S0, 64);
        unsigned b1 = (unsigned)__shfl((int)Q[(2 * kt + 1) * 2 + 1], S0, 64);
        unsigned a2 = (unsigned)__shfl((int)Q[(2 * kt) * 2 + 0], S1, 64);
        unsigned b2 = (unsigned)__shfl((int)Q[(2 * kt + 1) * 2 + 0], S1, 64);
        unsigned a3 = (unsigned)__shfl((int)Q[(2 * kt) * 2 + 1], S1, 64);
        unsigned b3 = (unsigned)__shfl((int)Q[(2 * kt + 1) * 2 + 1], S1, 64);
        union { unsigned u[4]; f16x8 v; } r;
        r.u[0] = hi ? b0 : a0; r.u[1] = hi ? b1 : a1;
        r.u[2] = hi ? b2 : a2; r.u[3] = hi ? b3 : a3;
        bf[kt] = r.v;
    }
}

// ---------------------------------------------------------------------------
// K_prepstats: blocks 0..147 = weight pre-transpose; blocks 148..151 = batch
// stats: x_center, x_mean, and xm2 analytically (means commute with linear
// maps). Fully block-parallel.
// ---------------------------------------------------------------------------
__global__ void k_prepstats(const float* __restrict__ Wc1, const float* __restrict__ Wc2,
                            const float* __restrict__ We1, const float* __restrict__ Wk1,
                            const float* __restrict__ We2, const float* __restrict__ Wk2,
                            const float* __restrict__ x, const float* __restrict__ W_coord,
                            float* __restrict__ ws) {
    if (blockIdx.x < 148) {
        int idx = blockIdx.x * 256 + threadIdx.x;
        if (idx >= WF_TOTAL) return;
        unsigned short* wsu = (unsigned short*)(ws + WS_WF);
        int local, v, lane, tile, lr, lg;
        float val;
        if (idx < OW2) {                       // Wc1 as A [o=64][c=128]
            local = idx - OW1; v = local & 7; lane = (local >> 3) & 63; tile = local >> 9;
            lr = lane & 15; lg = lane >> 4;
            int nt = tile >> 2, kt = tile & 3;
            int m = 16 * nt + lr, k = 32 * kt + 8 * lg + v;
            val = Wc1[k * 64 + m];
        } else if (idx < OWAE) {               // Wc2 as A [cc=128][o=64]
            local = idx - OW2; v = local & 7; lane = (local >> 3) & 63; tile = local >> 9;
            lr = lane & 15; lg = lane >> 4;
            int nt = tile >> 1, kt = tile & 1;
            int m = 16 * nt + lr, k = 32 * kt + 8 * lg + v;
            val = Wc2[k * 128 + m];
        } else if (idx < OWAK) {               // We1 rows 128.. as A [o=64][cd=128]
            local = idx - OWAE; v = local & 7; lane = (local >> 3) & 63; tile = local >> 9;
            lr = lane & 15; lg = lane >> 4;
            int nt = tile >> 2, kt = tile & 3;
            int m = 16 * nt + lr, k = 32 * kt + 8 * lg + v;
            val = We1[(128 + k) * 64 + m];
        } else if (idx < OWBE) {               // Wk1 rows 128.. as A [o=64][cd=128]
            local = idx - OWAK; v = local & 7; lane = (local >> 3) & 63; tile = local >> 9;
            lr = lane & 15; lg = lane >> 4;
            int nt = tile >> 2, kt = tile & 3;
            int m = 16 * nt + lr, k = 32 * kt + 8 * lg + v;
            val = Wk1[(128 + k) * 64 + m];
        } else if (idx < OWBK) {               // We2 as A [o2=64][o=64]
            local = idx - OWBE; v = local & 7; lane = (local >> 3) & 63; tile = local >> 9;
            lr = lane & 15; lg = lane >> 4;
            int nt = tile >> 1, kt = tile & 1;
            int m = 16 * nt + lr, k = 32 * kt + 8 * lg + v;
            val = We2[k * 64 + m];
        } else {                               // Wk2 as A [cat(pad16)][o=64]
            local = idx - OWBK; v = local & 7; lane = (local >> 3) & 63; tile = local >> 9;
            lr = lane & 15; lg = lane >> 4;
            int kt = tile & 1;
            int k = 32 * kt + 8 * lg + v;
            val = (lr < 4) ? Wk2[k * 4 + lr] : 0.0f;
        }
        wsu[idx] = (unsigned short)__builtin_bit_cast(unsigned short, (_Float16)val);
        return;
    }
    // ---- stats part (block-parallel) ----
    int b = blockIdx.x - 148;
    int tid = threadIdx.x, lane = tid & 63, w = tid >> 6;
    __shared__ float sred[4][30];
    __shared__ float sS[30];
    __shared__ float sxc[3];
    __shared__ float swb[10];
    __shared__ float sM[30];
    float v[30];
    const float* xp = x + (b * 256 + tid) * 30;
#pragma unroll
    for (int t = 0; t < 30; ++t) v[t] = xp[t];
#pragma unroll
    for (int t = 0; t < 30; ++t) {
        float s = v[t];
#pragma unroll
        for (int m = 1; m < 64; m <<= 1) s += __shfl_xor(s, m, 64);
        if (lane == 0) sred[w][t] = s;
    }
    __syncthreads();
    if (tid < 30) sS[tid] = sred[0][tid] + sred[1][tid] + sred[2][tid] + sred[3][tid];
    if (tid >= 64 && tid < 74) {            // wave 1: W_coord row means
        int s = tid - 64;
        float wb = 0.0f;
        for (int c = 0; c < 64; ++c) wb += W_coord[s * 64 + c];
        swb[s] = wb * (1.0f / 64.0f);
    }
    __syncthreads();
    if (tid < 3) {
        float s = 0.0f;
        for (int t = 0; t < 10; ++t) s += sS[t * 3 + tid];
        float xc = s * (1.0f / 2560.0f);
        sxc[tid] = xc;
        ws[WS_XC + b * 4 + tid] = xc;
    }
    __syncthreads();
    if (tid < 30) {
        int s = tid / 3, d = tid % 3;
        float w0 = sqrtf(0.1f), w1 = sqrtf(0.2f);
        float acc = 0.0f;
        for (int t = 0; t < 10; ++t) {
            float coef = ((s == 0) ? w0 : w1) * cosf(PI_F * (t + 0.5f) * s * 0.1f);
            acc += coef * (sS[t * 3 + d] * (1.0f / 256.0f) - sxc[d]);
        }
        sM[tid] = acc;
    }
    __syncthreads();
    if (tid < 3) {
        int d = tid;
        float s = 0.0f;
        for (int t = 0; t < 10; ++t) s += sM[t * 3 + d];
        float xm = s * 0.1f;
        ws[WS_XMEAN + b * 4 + d] = xm;
        float xm2 = xm;
        for (int t = 0; t < 10; ++t) xm2 += (sM[t * 3 + d] - xm) * swb[t];
        ws[WS_XM2 + b * 4 + d] = xm2;
    }
}

// ---------------------------------------------------------------------------
// K1: per-node: DCT, vel angles, hh embedding, xh/vh channels, PLUS fused
// edge-MLP rank-1 terms (bias_e/contrib_e; hh shared via block LDS).
// ---------------------------------------------------------------------------
__global__ void k_nodes(const float* __restrict__ x, const float* __restrict__ vel,
                        const float* __restrict__ h,
                        const float* __restrict__ W_emb, const float* __restrict__ b_emb,
                        const float* __restrict__ W_emb2, const float* __restrict__ b_emb2,
                        const float* __restrict__ W_coord, const float* __restrict__ W_vel,
                        const float* __restrict__ We1, const float* __restrict__ be1,
                        float* __restrict__ ws) {
    int nd = threadIdx.x >> 6;
    int node = blockIdx.x * 4 + nd;
    int lane = threadIdx.x & 63;
    int b = node >> 8, n = node & 255;
    __shared__ float shh[4][64];
    float xc[3], xm[3];
#pragma unroll
    for (int d = 0; d < 3; ++d) {
        xc[d] = ws[WS_XC + b * 4 + d];
        xm[d] = ws[WS_XMEAN + b * 4 + d];
    }
    const float* xp = x + node * 30;
    const float* vp = vel + node * 30;
    float xs[10][3], vl[10][3];
#pragma unroll
    for (int t = 0; t < 10; ++t)
#pragma unroll
        for (int d = 0; d < 3; ++d) {
            xs[t][d] = xp[t * 3 + d] - xc[d];
            vl[t][d] = vp[t * 3 + d];
        }
    float ang[10];
#pragma unroll
    for (int t = 0; t < 10; ++t) {
        int tp = (t == 0) ? 0 : (t - 1);
        float dot = 0.0f, n1 = 0.0f, n2 = 0.0f;
#pragma unroll
        for (int d = 0; d < 3; ++d) {
            float a = vl[tp][d], c = vl[t][d];
            dot += a * c; n1 += a * a; n2 += c * c;
        }
        float cv = dot / ((sqrtf(n1) + EPS_F) * (sqrtf(n2) + EPS_F));
        cv = fminf(1.0f, fmaxf(-1.0f, cv));
        ang[t] = acosf(cv);
    }
    float xd[10][3], vd[10][3];
    float w0 = sqrtf(0.1f), w1 = sqrtf(0.2f);
#pragma unroll
    for (int s = 0; s < 10; ++s) {
        float a0 = 0, a1 = 0, a2 = 0, c0 = 0, c1 = 0, c2 = 0;
#pragma unroll
        for (int t = 0; t < 10; ++t) {
            float coef = ((s == 0) ? w0 : w1) * cosf(PI_F * (t + 0.5f) * s * 0.1f);
            a0 += coef * xs[t][0]; a1 += coef * xs[t][1]; a2 += coef * xs[t][2];
            c0 += coef * vl[t][0]; c1 += coef * vl[t][1]; c2 += coef * vl[t][2];
        }
        xd[s][0] = a0; xd[s][1] = a1; xd[s][2] = a2;
        vd[s][0] = c0; vd[s][1] = c1; vd[s][2] = c2;
    }
    const float* hp = h + node * 10;
    float acc;
    if (lane < 32) {
        acc = b_emb[lane];
#pragma unroll
        for (int t = 0; t < 10; ++t) acc += hp[t] * W_emb[t * 32 + lane];
    } else {
        int o2 = lane - 32;
        acc = b_emb2[o2];
#pragma unroll
        for (int t = 0; t < 10; ++t) acc += ang[t] * W_emb2[t * 32 + o2];
    }
    ws[WS_HH + node * 64 + lane] = acc;
    shh[nd][lane] = acc;
    float xh[3] = {xm[0], xm[1], xm[2]};
    float vh[3] = {0.0f, 0.0f, 0.0f};
#pragma unroll
    for (int t = 0; t < 10; ++t) {
        float wc = W_coord[t * 64 + lane];
        float wv = W_vel[t * 64 + lane];
#pragma unroll
        for (int d = 0; d < 3; ++d) {
            xh[d] += (xd[t][d] - xm[d]) * wc;
            vh[d] += vd[t][d] * wv;
        }
    }
#pragma unroll
    for (int d = 0; d < 3; ++d)
        ws[WS_XH + (node * 64 + lane) * 3 + d] = xh[d];
    // pair-packed fp16 coordT: channel c=lane (xh), 64+lane (vh)
    unsigned short* cth = (unsigned short*)(ws + WS_CTH) + (size_t)b * 192 * 256 * 2;
    int px = lane >> 1, sx = lane & 1;
#pragma unroll
    for (int d = 0; d < 3; ++d) {
        cth[((px * 3 + d) * 256 + n) * 2 + sx] =
            __builtin_bit_cast(unsigned short, (_Float16)xh[d]);
        cth[(((32 + px) * 3 + d) * 256 + n) * 2 + sx] =
            __builtin_bit_cast(unsigned short, (_Float16)vh[d]);
    }
    // ---- fused contrib1: bias_e/contrib_e from shared hh ----
    __syncthreads();
    int o = lane;
    float a1 = be1[o], a2 = 0.0f;
    for (int t = 0; t < 64; ++t) {
        float hv = shh[nd][t];
        a1 = fmaf(hv, We1[t * 64 + o], a1);
        a2 = fmaf(hv, We1[(64 + t) * 64 + o], a2);
    }
    ws[WS_BIASE + node * 64 + o] = a1;
    ws[WS_CONTRE + node * 64 + o] = a2;
}

// ---------------------------------------------------------------------------
// K_tail: node_new MLP + category-head rank-1 terms, THEN x_out prediction
// head + inverse DCT (independent work fused; both runnable after PASS0).
// ---------------------------------------------------------------------------
__global__ void k_tail(const float* __restrict__ Wn1, const float* __restrict__ bn1,
                       const float* __restrict__ Wn2, const float* __restrict__ bn2,
                       const float* __restrict__ Wk1, const float* __restrict__ bk1,
                       const float* __restrict__ W_pred,
                       float* __restrict__ ws, float* __restrict__ out) {
    int nd = threadIdx.x >> 6;
    int o = threadIdx.x & 63;
    int node = blockIdx.x * 4 + nd;
    int b = node >> 8;
    __shared__ float sg[4][64], snn[4][64];
    __shared__ float sxp[4][60];
    const float* hp = ws + WS_HH + node * 64;
    const float* ap = ws + WS_AGG + node * 64;
    float acc = bn1[o];
    for (int t = 0; t < 64; ++t) acc = fmaf(hp[t], Wn1[t * 64 + o], acc);
    for (int t = 0; t < 64; ++t) acc = fmaf(ap[t], Wn1[(64 + t) * 64 + o], acc);
    sg[nd][o] = silu(acc);
    __syncthreads();
    acc = bn2[o];
    for (int t = 0; t < 64; ++t) acc = fmaf(sg[nd][t], Wn2[t * 64 + o], acc);
    snn[nd][o] = silu(acc);
    __syncthreads();
    float bk = bk1[o], ck = 0.0f;
    for (int t = 0; t < 64; ++t) {
        float v = snn[nd][t];
        bk = fmaf(v, Wk1[t * 64 + o], bk);
        ck = fmaf(v, Wk1[(64 + t) * 64 + o], ck);
    }
    ws[WS_BIASK + node * 64 + o] = bk;
    ws[WS_CONTRK + node * 64 + o] = ck;
    // ---- x_out head (independent; lanes < 60) ----
    float xm2[3];
#pragma unroll
    for (int d = 0; d < 3; ++d) xm2[d] = ws[WS_XM2 + b * 4 + d];
    if (o < 60) {
        int o2 = o / 3, d = o % 3;
        const float* p = ws + WS_XH + node * 192;
        float a = xm2[d];
        for (int c = 0; c < 64; ++c) a += (p[c * 3 + d] - xm2[d]) * W_pred[c * 20 + o2];
        sxp[nd][o] = a;
    }
    __syncthreads();
    if (o < 60) {
        int s = o / 3, d = o % 3;
        float w0 = sqrtf(0.05f), w1 = sqrtf(0.1f);
        float a = ws[WS_XC + b * 4 + d];
#pragma unroll
        for (int t = 0; t < 20; ++t) {
            float coef = ((t == 0) ? w0 : w1) * cosf(PI_F * (s + 0.5f) * t * 0.05f);
            a += coef * sxp[nd][t * 3 + d];
        }
        out[(node * 20 + s) * 3 + d] = a;
    }
}

// ---------------------------------------------------------------------------
// K_pair<PASS>: MFMA pair pipeline, swapped operands (A=weights, B=activations,
// D cols = j = lane&15 throughout). Layer transitions fully in-register via
// pk2 + __shfl within lane groups {lr, lr+16, lr+32, lr+48}.
// Block: 512 threads = 8 waves; waves 0-3 -> i0, 4-7 -> i0+1; wave jw covers
// j in [64*jw, 64*jw+64), 16 j per mt iteration.
// amdgpu_waves_per_eu(4,4): R12/R13-measured best (no spills).
// sched_barrier(0) stage fences: REQUIRED (R15). L2 window un-split (R18):
// Q2[16] + single fence — +8 VGPR, 2x scheduler window in longest stage.
// ---------------------------------------------------------------------------
template<int PASS>
__global__ __attribute__((amdgpu_waves_per_eu(4, 4))) __launch_bounds__(512)
void k_pair(
    const float* __restrict__ bc1, const float* __restrict__ bc2,
    const float* __restrict__ bB,
    float* __restrict__ ws, float* __restrict__ out) {

    __shared__ __align__(16) unsigned short WL[28672];  // W1(8192) W2(8192) WA(8192) WB(4096)
    __shared__ __align__(16) unsigned sciu[2][192];     // i-rows, fp16 pair-packed
    __shared__ __align__(16) float sb1[64];
    __shared__ __align__(16) float sb2[128];
    __shared__ __align__(16) float sbB[64];
    __shared__ __align__(16) float sbias[2][64];
    __shared__ float sred[8][64];

    const int tid = threadIdx.x;
    const int b = blockIdx.y;
    const int i0 = blockIdx.x * 2;
    const unsigned* cTu = (const unsigned*)(ws + WS_CTH) + (size_t)b * 192 * 256;
    const unsigned short* wsu = (const unsigned short*)(ws + WS_WF);

    // ---- stage fragment-major weights (coalesced uint4 copies) ----
    {
        const uint4* s0 = (const uint4*)(wsu + OW1);            // W1+W2: 2048 u4
        uint4* d0 = (uint4*)(&WL[0]);
        for (int t = tid; t < 2048; t += 512) d0[t] = s0[t];
        const uint4* s1 = (const uint4*)(wsu + (PASS ? OWAK : OWAE));
        uint4* d1 = (uint4*)(&WL[16384]);
        for (int t = tid; t < 1024; t += 512) d1[t] = s1[t];
        const uint4* s2 = (const uint4*)(wsu + (PASS ? OWBK : OWBE));
        uint4* d2 = (uint4*)(&WL[24576]);
        int nb = PASS ? 128 : 512;
        for (int t = tid; t < nb; t += 512) d2[t] = s2[t];
    }
    for (int idx = tid; idx < 384; idx += 512) {
        int ii2 = idx / 192, q = idx % 192;
        sciu[ii2][q] = cTu[q * 256 + (i0 + ii2)];
    }
    if (tid < 64)  sb1[tid] = bc1[tid];
    if (tid < 128) sb2[tid] = bc2[tid];
    if (tid < 64)  sbB[tid] = (PASS == 0) ? bB[tid] : (tid < 4 ? bB[tid] : 0.0f);
    {
        const float* bias = ws + ((PASS == 0) ? WS_BIASE : WS_BIASK);
        if (tid < 128) {
            int ii = tid >> 6, o = tid & 63;
            sbias[ii][o] = bias[(b * 256 + i0 + ii) * 64 + o];
        }
    }
    __syncthreads();

    const int w = tid >> 6, lane = tid & 63;
    const int lr = lane & 15, lg = lane >> 4;
    const int ii = w >> 2, jw = w & 3;
    const int i = i0 + ii;
    const float* contrib = ws + ((PASS == 0) ? WS_CONTRE : WS_CONTRK) + b * 256 * 64;

    const int S0 = ((lg & 1) << 5) + lr;
    const int S1 = S0 + 16;
    const bool hi = (lg >> 1) != 0;

    const unsigned short* W1L = WL;
    const unsigned short* W2L = WL + 8192;
    const unsigned short* WAL = WL + 16384;
    const unsigned short* WBL = WL + 24576;

    // hoist mt-invariant i-row channel pairs (16 pairs x 3 dims) to registers
    unsigned cia[48];
#pragma unroll
    for (int kt = 0; kt < 4; ++kt)
#pragma unroll
        for (int q = 0; q < 4; ++q) {
            int p3 = (16 * kt + 4 * lg + q) * 3;
#pragma unroll
            for (int d = 0; d < 3; ++d)
                cia[(kt * 4 + q) * 3 + d] = sciu[ii][p3 + d];
        }

    float pacc[16];
#pragma unroll
    for (int t = 0; t < 16; ++t) pacc[t] = 0.0f;

#pragma unroll 1
    for (int mt = 0; mt < 4; ++mt) {
        const int jbase = 64 * jw + 16 * mt;
        const int j = jbase + lr;

        // ---- dist B-fragments, packed fp16: dword q of as[kt] = channel pair
        // p = 16kt+4lg+q = channels {2p, 2p+1} for column j.
        f16x8 as[4];
#pragma unroll
        for (int kt = 0; kt < 4; ++kt) {
            union { f16x8 v; unsigned u[4]; } r;
#pragma unroll
            for (int q = 0; q < 4; ++q) {
                int p3 = (16 * kt + 4 * lg + q) * 3;
                int ci = (kt * 4 + q) * 3;
                f16x2 d0 = __builtin_bit_cast(f16x2, cia[ci + 0]) -
                           __builtin_bit_cast(f16x2, cTu[(p3 + 0) * 256 + j]);
                f16x2 d1 = __builtin_bit_cast(f16x2, cia[ci + 1]) -
                           __builtin_bit_cast(f16x2, cTu[(p3 + 1) * 256 + j]);
                f16x2 d2 = __builtin_bit_cast(f16x2, cia[ci + 2]) -
                           __builtin_bit_cast(f16x2, cTu[(p3 + 2) * 256 + j]);
                f16x2 s = d0 * d0 + d1 * d1 + d2 * d2;
                r.u[q] = pk2(sqrtf((float)s[0]), sqrtf((float)s[1]));
            }
            as[kt] = r.v;
        }
        __builtin_amdgcn_sched_barrier(0);

        // ---- L1: t1 = silu(Wc1 . dist), rows o, cols j.  K=128 ----
        unsigned Q1[8];
#pragma unroll
        for (int nt = 0; nt < 4; ++nt) {
            float4 bv = *(const float4*)&sb1[16 * nt + 4 * lg];
            f32x4 d = {bv.x, bv.y, bv.z, bv.w};
#pragma unroll
            for (int kt = 0; kt < 4; ++kt) {
                f16x8 af = *(const f16x8*)&W1L[((nt * 4 + kt) * 64 + lane) * 8];
                d = __builtin_amdgcn_mfma_f32_16x16x32_f16(af, as[kt], d, 0, 0, 0);
            }
            Q1[nt * 2 + 0] = pk2(silu(d[0]), silu(d[1]));
            Q1[nt * 2 + 1] = pk2(silu(d[2]), silu(d[3]));
        }
        f16x8 a2[2];
        xfrag<2>(Q1, S0, S1, hi, a2);
        __builtin_amdgcn_sched_barrier(0);

        // ---- L2: cd = silu(Wc2 . t1), rows cc (128), cols j.  K=64 ----
        // Un-split (R18): full Q2[16], one fence — bigger scheduler window.
        f16x8 a3[4];
        {
            unsigned Q2[16];
#pragma unroll
            for (int ntc = 0; ntc < 8; ++ntc) {
                float4 bv = *(const float4*)&sb2[16 * ntc + 4 * lg];
                f32x4 d = {bv.x, bv.y, bv.z, bv.w};
#pragma unroll
                for (int kt = 0; kt < 2; ++kt) {
                    f16x8 af = *(const f16x8*)&W2L[((ntc * 2 + kt) * 64 + lane) * 8];
                    d = __builtin_amdgcn_mfma_f32_16x16x32_f16(af, a2[kt], d, 0, 0, 0);
                }
                Q2[ntc * 2 + 0] = pk2(silu(d[0]), silu(d[1]));
                Q2[ntc * 2 + 1] = pk2(silu(d[2]), silu(d[3]));
            }
            xfrag<4>(Q2, S0, S1, hi, a3);
        }
        __builtin_amdgcn_sched_barrier(0);

        // ---- L3: e1 = silu(bias + contrib_j + WA . cd), rows o, cols j. K=128 ----
        unsigned Q3[8];
#pragma unroll
        for (int nt = 0; nt < 4; ++nt) {
            float4 bv = *(const float4*)&sbias[ii][16 * nt + 4 * lg];
            float4 ce = *(const float4*)&contrib[j * 64 + 16 * nt + 4 * lg];
            f32x4 d = {bv.x + ce.x, bv.y + ce.y, bv.z + ce.z, bv.w + ce.w};
#pragma unroll
            for (int kt = 0; kt < 4; ++kt) {
                f16x8 af = *(const f16x8*)&WAL[((nt * 4 + kt) * 64 + lane) * 8];
                d = __builtin_amdgcn_mfma_f32_16x16x32_f16(af, a3[kt], d, 0, 0, 0);
            }
            Q3[nt * 2 + 0] = pk2(silu(d[0]), silu(d[1]));
            Q3[nt * 2 + 1] = pk2(silu(d[2]), silu(d[3]));
        }
        f16x8 a4[2];
        xfrag<2>(Q3, S0, S1, hi, a4);
        __builtin_amdgcn_sched_barrier(0);

        // ---- L4 ----
        if (PASS == 0) {
            // edge = silu(We2 . e1), rows o2, cols j; mask j==i; accumulate col-sums
#pragma unroll
            for (int nt = 0; nt < 4; ++nt) {
                float4 bv = *(const float4*)&sbB[16 * nt + 4 * lg];
                f32x4 d = {bv.x, bv.y, bv.z, bv.w};
#pragma unroll
                for (int kt = 0; kt < 2; ++kt) {
                    f16x8 af = *(const f16x8*)&WBL[((nt * 2 + kt) * 64 + lane) * 8];
                    d = __builtin_amdgcn_mfma_f32_16x16x32_f16(af, a4[kt], d, 0, 0, 0);
                }
                float m = (j == i) ? 0.0f : 1.0f;
#pragma unroll
                for (int r = 0; r < 4; ++r)
                    pacc[nt * 4 + r] += m * silu(d[r]);
            }
        } else {
            // logits rows = cat (0..3 real, rest zero-weight), cols j
            f32x4 d;
            if (lg == 0) {
                float4 bv = *(const float4*)&sbB[0];
                d = {bv.x, bv.y, bv.z, bv.w};
            } else {
                d = {0.0f, 0.0f, 0.0f, 0.0f};
            }
#pragma unroll
            for (int kt = 0; kt < 2; ++kt) {
                f16x8 af = *(const f16x8*)&WBL[(kt * 64 + lane) * 8];
                d = __builtin_amdgcn_mfma_f32_16x16x32_f16(af, a4[kt], d, 0, 0, 0);
            }
            if (lg == 0) {
                float l0 = silu(d[0]), l1 = silu(d[1]), l2 = silu(d[2]), l3 = silu(d[3]);
                float mx = fmaxf(fmaxf(l0, l1), fmaxf(l2, l3));
                float e0 = __expf(l0 - mx), e1 = __expf(l1 - mx);
                float e2 = __expf(l2 - mx), e3 = __expf(l3 - mx);
                float inv = __builtin_amdgcn_rcpf(e0 + e1 + e2 + e3);
                float4 r = make_float4(e0 * inv, e1 * inv, e2 * inv, e3 * inv);
                *(float4*)&out[61440 + (((b * 256 + i) * 256 + j) << 2)] = r;
            }
        }
        __builtin_amdgcn_sched_barrier(0);
    }

    if (PASS == 0) {
        // reduce over the 16 j-lanes (lr) of each row group
#pragma unroll
        for (int t = 0; t < 16; ++t) {
            pacc[t] += __shfl_xor(pacc[t], 1, 64);
            pacc[t] += __shfl_xor(pacc[t], 2, 64);
            pacc[t] += __shfl_xor(pacc[t], 4, 64);
            pacc[t] += __shfl_xor(pacc[t], 8, 64);
        }
        if (lr == 0) {
#pragma unroll
            for (int nt = 0; nt < 4; ++nt)
#pragma unroll
                for (int r = 0; r < 4; ++r)
                    sred[w][16 * nt + 4 * lg + r] = pacc[nt * 4 + r];
        }
        __syncthreads();
        if (tid < 128) {
            int iw = tid >> 6, o = tid & 63;
            float s = sred[iw * 4 + 0][o] + sred[iw * 4 + 1][o] +
                      sred[iw * 4 + 2][o] + sred[iw * 4 + 3][o];
            ws[WS_AGG + (b * 256 + i0 + iw) * 64 + o] = s;
        }
    }
}

// ---------------------------------------------------------------------------
extern "C" void kernel_launch(void* const* d_in, const int* in_sizes, int n_in,
                              void* d_out, int out_size, void* d_ws, size_t ws_size,
                              hipStream_t stream) {
    (void)in_sizes; (void)n_in; (void)out_size; (void)ws_size;
    const float* h      = (const float*)d_in[0];
    const float* x      = (const float*)d_in[1];
    const float* vel    = (const float*)d_in[2];
    const float* W_emb  = (const float*)d_in[3];
    const float* b_emb  = (const float*)d_in[4];
    const float* W_emb2 = (const float*)d_in[5];
    const float* b_emb2 = (const float*)d_in[6];
    const float* W_coord= (const float*)d_in[7];
    const float* W_vel  = (const float*)d_in[8];
    const float* W_pred = (const float*)d_in[9];
    const float* Wc1    = (const float*)d_in[10];
    const float* bc1    = (const float*)d_in[11];
    const float* Wc2    = (const float*)d_in[12];
    const float* bc2    = (const float*)d_in[13];
    const float* We1    = (const float*)d_in[14];
    const float* be1    = (const float*)d_in[15];
    const float* We2    = (const float*)d_in[16];
    const float* be2    = (const float*)d_in[17];
    const float* Wn1    = (const float*)d_in[18];
    const float* bn1    = (const float*)d_in[19];
    const float* Wn2    = (const float*)d_in[20];
    const float* bn2    = (const float*)d_in[21];
    const float* Wk1    = (const float*)d_in[22];
    const float* bk1    = (const float*)d_in[23];
    const float* Wk2    = (const float*)d_in[24];
    const float* bk2    = (const float*)d_in[25];
    float* ws  = (float*)d_ws;
    float* out = (float*)d_out;

    k_prepstats<<<152, 256, 0, stream>>>(Wc1, Wc2, We1, Wk1, We2, Wk2, x, W_coord, ws);
    k_nodes<<<256, 256, 0, stream>>>(x, vel, h, W_emb, b_emb, W_emb2, b_emb2,
                                     W_coord, W_vel, We1, be1, ws);
    k_pair<0><<<dim3(128, 4), 512, 0, stream>>>(bc1, bc2, be2, ws, out);
    k_tail<<<256, 256, 0, stream>>>(Wn1, bn1, Wn2, bn2, Wk1, bk1, W_pred, ws, out);
    k_pair<1><<<dim3(128, 4), 512, 0, stream>>>(bc1, bc2, bk2, ws, out);
}

// Round 19
// 145.185 us; speedup vs baseline: 1.0423x; 1.0423x over previous
//
#include <hip/hip_runtime.h>
#include <math.h>

// ---------------------------------------------------------------------------
// EqMotion fused implementation. Pair passes on MFMA (fp16, swapped operands,
// in-register layer transitions), rest fp32 VALU.
// B=4, N=256, T_IN=10, T_OUT=20, HID=64, HALF=32, HC=64, NCAT=4.
// Outputs: x_out [4,256,20,3] (61440 f32) then category [4,256,256,4].
// coordT: channel-PAIR-packed fp16, [b][p*3+d][j] uint (= ch 2p, 2p+1).
// R15: sched_barrier(0) stage fences in k_pair are LOAD-BEARING (removal ->
// 900MB spills, 5x). R16: no serial single-thread global-load tails.
// R18: L2 fence-window widening = null; k_xout+k_nodes2 fusion = -6us.
// This is the R17 measured-best configuration (145.3 us).
// ---------------------------------------------------------------------------

constexpr int WS_XC     = 0;                       // [4][3] stride 4
constexpr int WS_XMEAN  = 16;                      // [4][3] stride 4
constexpr int WS_XM2    = 32;                      // [4][3] stride 4
constexpr int WS_CTH    = 64;                      // [4][192][256] uint (fp16 pairs)
constexpr int WS_XH     = WS_CTH + 4*192*256;      // [4][256][64][3] f32
constexpr int WS_HH     = WS_XH + 4*256*64*3;      // [4][256][64]
constexpr int WS_BIASE  = WS_HH + 4*256*64;        // [4][256][64]
constexpr int WS_CONTRE = WS_BIASE + 4*256*64;     // [4][256][64]  (natural [n][o])
constexpr int WS_AGG    = WS_CONTRE + 4*256*64;    // [4][256][64]
constexpr int WS_BIASK  = WS_AGG + 4*256*64;       // [4][256][64]
constexpr int WS_CONTRK = WS_BIASK + 4*256*64;     // [4][256][64]  (natural [n][o])
constexpr int WS_WF     = WS_CONTRK + 4*256*64;    // 37888 ushorts (fragment-major f16 weights)

// fragment-major weight regions, in ushort units within WS_WF
constexpr int OW1  = 0;      // Wc1 as A [o][c]     64x128 -> 8192
constexpr int OW2  = 8192;   // Wc2 as A [cc][o]   128x64  -> 8192
constexpr int OWAE = 16384;  // We1[128:256] as A [o][cd]  -> 8192
constexpr int OWAK = 24576;  // Wk1[128:256] as A [o][cd]  -> 8192
constexpr int OWBE = 32768;  // We2 as A [o2][o]    64x64  -> 4096
constexpr int OWBK = 36864;  // Wk2 as A [cat][o] (pad16)  -> 1024
constexpr int WF_TOTAL = 37888;

#define PI_F 3.14159265358979323846f
#define EPS_F 1e-6f

typedef _Float16 f16x8 __attribute__((ext_vector_type(8)));
typedef _Float16 f16x2 __attribute__((ext_vector_type(2)));
typedef float f32x4 __attribute__((ext_vector_type(4)));

__device__ __forceinline__ float silu(float v) {
    float t = 1.0f + __expf(-v);
    return v * __builtin_amdgcn_rcpf(t);
}

__device__ __forceinline__ unsigned pk2(float a, float b) {
    union { _Float16 h[2]; unsigned u; } x;
    x.h[0] = (_Float16)a; x.h[1] = (_Float16)b;
    return x.u;
}

// layer transition: Q[ns][q] packed fp16 pairs (ns = 2*KT tiles, q=0/1) ->
// B-fragments for next MFMA. Per-lane mapping (derivation verified):
// slot (kt, v) <- lane 32*(lg&1) + 16*(v>=4) + lr, reg Q[2kt+(lg>>1)][(v&3)>>1].
template<int KT>
__device__ __forceinline__ void xfrag(const unsigned* Q, int S0, int S1, bool hi,
                                      f16x8* bf) {
#pragma unroll
    for (int kt = 0; kt < KT; ++kt) {
        unsigned a0 = (unsigned)__shfl((int)Q[(2 * kt) * 2 + 0], S0, 64);
        unsigned b0 = (unsigned)__shfl((int)Q[(2 * kt + 1) * 2 + 0], S0, 64);
        unsigned a1 = (unsigned)__shfl((int)Q[(2 * kt) * 2 + 1], S0, 64);
        unsigned b1 = (unsigned)__shfl((int)Q[(2 * kt + 1) * 2 + 1], S0, 64);
        unsigned a2 = (unsigned)__shfl((int)Q[(2 * kt) * 2 + 0], S1, 64);
        unsigned b2 = (unsigned)__shfl((int)Q[(2 * kt + 1) * 2 + 0], S1, 64);
        unsigned a3 = (unsigned)__shfl((int)Q[(2 * kt) * 2 + 1], S1, 64);
        unsigned b3 = (unsigned)__shfl((int)Q[(2 * kt + 1) * 2 + 1], S1, 64);
        union { unsigned u[4]; f16x8 v; } r;
        r.u[0] = hi ? b0 : a0; r.u[1] = hi ? b1 : a1;
        r.u[2] = hi ? b2 : a2; r.u[3] = hi ? b3 : a3;
        bf[kt] = r.v;
    }
}

// ---------------------------------------------------------------------------
// K_prepstats: blocks 0..147 = weight pre-transpose; blocks 148..151 = batch
// stats: x_center, x_mean, and xm2 analytically (means commute with linear
// maps). Fully block-parallel.
// ---------------------------------------------------------------------------
__global__ void k_prepstats(const float* __restrict__ Wc1, const float* __restrict__ Wc2,
                            const float* __restrict__ We1, const float* __restrict__ Wk1,
                            const float* __restrict__ We2, const float* __restrict__ Wk2,
                            const float* __restrict__ x, const float* __restrict__ W_coord,
                            float* __restrict__ ws) {
    if (blockIdx.x < 148) {
        int idx = blockIdx.x * 256 + threadIdx.x;
        if (idx >= WF_TOTAL) return;
        unsigned short* wsu = (unsigned short*)(ws + WS_WF);
        int local, v, lane, tile, lr, lg;
        float val;
        if (idx < OW2) {                       // Wc1 as A [o=64][c=128]
            local = idx - OW1; v = local & 7; lane = (local >> 3) & 63; tile = local >> 9;
            lr = lane & 15; lg = lane >> 4;
            int nt = tile >> 2, kt = tile & 3;
            int m = 16 * nt + lr, k = 32 * kt + 8 * lg + v;
            val = Wc1[k * 64 + m];
        } else if (idx < OWAE) {               // Wc2 as A [cc=128][o=64]
            local = idx - OW2; v = local & 7; lane = (local >> 3) & 63; tile = local >> 9;
            lr = lane & 15; lg = lane >> 4;
            int nt = tile >> 1, kt = tile & 1;
            int m = 16 * nt + lr, k = 32 * kt + 8 * lg + v;
            val = Wc2[k * 128 + m];
        } else if (idx < OWAK) {               // We1 rows 128.. as A [o=64][cd=128]
            local = idx - OWAE; v = local & 7; lane = (local >> 3) & 63; tile = local >> 9;
            lr = lane & 15; lg = lane >> 4;
            int nt = tile >> 2, kt = tile & 3;
            int m = 16 * nt + lr, k = 32 * kt + 8 * lg + v;
            val = We1[(128 + k) * 64 + m];
        } else if (idx < OWBE) {               // Wk1 rows 128.. as A [o=64][cd=128]
            local = idx - OWAK; v = local & 7; lane = (local >> 3) & 63; tile = local >> 9;
            lr = lane & 15; lg = lane >> 4;
            int nt = tile >> 2, kt = tile & 3;
            int m = 16 * nt + lr, k = 32 * kt + 8 * lg + v;
            val = Wk1[(128 + k) * 64 + m];
        } else if (idx < OWBK) {               // We2 as A [o2=64][o=64]
            local = idx - OWBE; v = local & 7; lane = (local >> 3) & 63; tile = local >> 9;
            lr = lane & 15; lg = lane >> 4;
            int nt = tile >> 1, kt = tile & 1;
            int m = 16 * nt + lr, k = 32 * kt + 8 * lg + v;
            val = We2[k * 64 + m];
        } else {                               // Wk2 as A [cat(pad16)][o=64]
            local = idx - OWBK; v = local & 7; lane = (local >> 3) & 63; tile = local >> 9;
            lr = lane & 15; lg = lane >> 4;
            int kt = tile & 1;
            int k = 32 * kt + 8 * lg + v;
            val = (lr < 4) ? Wk2[k * 4 + lr] : 0.0f;
        }
        wsu[idx] = (unsigned short)__builtin_bit_cast(unsigned short, (_Float16)val);
        return;
    }
    // ---- stats part (block-parallel) ----
    int b = blockIdx.x - 148;
    int tid = threadIdx.x, lane = tid & 63, w = tid >> 6;
    __shared__ float sred[4][30];
    __shared__ float sS[30];
    __shared__ float sxc[3];
    __shared__ float swb[10];
    __shared__ float sM[30];
    float v[30];
    const float* xp = x + (b * 256 + tid) * 30;
#pragma unroll
    for (int t = 0; t < 30; ++t) v[t] = xp[t];
#pragma unroll
    for (int t = 0; t < 30; ++t) {
        float s = v[t];
#pragma unroll
        for (int m = 1; m < 64; m <<= 1) s += __shfl_xor(s, m, 64);
        if (lane == 0) sred[w][t] = s;
    }
    __syncthreads();
    if (tid < 30) sS[tid] = sred[0][tid] + sred[1][tid] + sred[2][tid] + sred[3][tid];
    if (tid >= 64 && tid < 74) {            // wave 1: W_coord row means
        int s = tid - 64;
        float wb = 0.0f;
        for (int c = 0; c < 64; ++c) wb += W_coord[s * 64 + c];
        swb[s] = wb * (1.0f / 64.0f);
    }
    __syncthreads();
    if (tid < 3) {
        float s = 0.0f;
        for (int t = 0; t < 10; ++t) s += sS[t * 3 + tid];
        float xc = s * (1.0f / 2560.0f);
        sxc[tid] = xc;
        ws[WS_XC + b * 4 + tid] = xc;
    }
    __syncthreads();
    if (tid < 30) {
        int s = tid / 3, d = tid % 3;
        float w0 = sqrtf(0.1f), w1 = sqrtf(0.2f);
        float acc = 0.0f;
        for (int t = 0; t < 10; ++t) {
            float coef = ((s == 0) ? w0 : w1) * cosf(PI_F * (t + 0.5f) * s * 0.1f);
            acc += coef * (sS[t * 3 + d] * (1.0f / 256.0f) - sxc[d]);
        }
        sM[tid] = acc;
    }
    __syncthreads();
    if (tid < 3) {
        int d = tid;
        float s = 0.0f;
        for (int t = 0; t < 10; ++t) s += sM[t * 3 + d];
        float xm = s * 0.1f;
        ws[WS_XMEAN + b * 4 + d] = xm;
        float xm2 = xm;
        for (int t = 0; t < 10; ++t) xm2 += (sM[t * 3 + d] - xm) * swb[t];
        ws[WS_XM2 + b * 4 + d] = xm2;
    }
}

// ---------------------------------------------------------------------------
// K1: per-node: DCT, vel angles, hh embedding, xh/vh channels, PLUS fused
// edge-MLP rank-1 terms (bias_e/contrib_e; hh shared via block LDS).
// ---------------------------------------------------------------------------
__global__ void k_nodes(const float* __restrict__ x, const float* __restrict__ vel,
                        const float* __restrict__ h,
                        const float* __restrict__ W_emb, const float* __restrict__ b_emb,
                        const float* __restrict__ W_emb2, const float* __restrict__ b_emb2,
                        const float* __restrict__ W_coord, const float* __restrict__ W_vel,
                        const float* __restrict__ We1, const float* __restrict__ be1,
                        float* __restrict__ ws) {
    int nd = threadIdx.x >> 6;
    int node = blockIdx.x * 4 + nd;
    int lane = threadIdx.x & 63;
    int b = node >> 8, n = node & 255;
    __shared__ float shh[4][64];
    float xc[3], xm[3];
#pragma unroll
    for (int d = 0; d < 3; ++d) {
        xc[d] = ws[WS_XC + b * 4 + d];
        xm[d] = ws[WS_XMEAN + b * 4 + d];
    }
    const float* xp = x + node * 30;
    const float* vp = vel + node * 30;
    float xs[10][3], vl[10][3];
#pragma unroll
    for (int t = 0; t < 10; ++t)
#pragma unroll
        for (int d = 0; d < 3; ++d) {
            xs[t][d] = xp[t * 3 + d] - xc[d];
            vl[t][d] = vp[t * 3 + d];
        }
    float ang[10];
#pragma unroll
    for (int t = 0; t < 10; ++t) {
        int tp = (t == 0) ? 0 : (t - 1);
        float dot = 0.0f, n1 = 0.0f, n2 = 0.0f;
#pragma unroll
        for (int d = 0; d < 3; ++d) {
            float a = vl[tp][d], c = vl[t][d];
            dot += a * c; n1 += a * a; n2 += c * c;
        }
        float cv = dot / ((sqrtf(n1) + EPS_F) * (sqrtf(n2) + EPS_F));
        cv = fminf(1.0f, fmaxf(-1.0f, cv));
        ang[t] = acosf(cv);
    }
    float xd[10][3], vd[10][3];
    float w0 = sqrtf(0.1f), w1 = sqrtf(0.2f);
#pragma unroll
    for (int s = 0; s < 10; ++s) {
        float a0 = 0, a1 = 0, a2 = 0, c0 = 0, c1 = 0, c2 = 0;
#pragma unroll
        for (int t = 0; t < 10; ++t) {
            float coef = ((s == 0) ? w0 : w1) * cosf(PI_F * (t + 0.5f) * s * 0.1f);
            a0 += coef * xs[t][0]; a1 += coef * xs[t][1]; a2 += coef * xs[t][2];
            c0 += coef * vl[t][0]; c1 += coef * vl[t][1]; c2 += coef * vl[t][2];
        }
        xd[s][0] = a0; xd[s][1] = a1; xd[s][2] = a2;
        vd[s][0] = c0; vd[s][1] = c1; vd[s][2] = c2;
    }
    const float* hp = h + node * 10;
    float acc;
    if (lane < 32) {
        acc = b_emb[lane];
#pragma unroll
        for (int t = 0; t < 10; ++t) acc += hp[t] * W_emb[t * 32 + lane];
    } else {
        int o2 = lane - 32;
        acc = b_emb2[o2];
#pragma unroll
        for (int t = 0; t < 10; ++t) acc += ang[t] * W_emb2[t * 32 + o2];
    }
    ws[WS_HH + node * 64 + lane] = acc;
    shh[nd][lane] = acc;
    float xh[3] = {xm[0], xm[1], xm[2]};
    float vh[3] = {0.0f, 0.0f, 0.0f};
#pragma unroll
    for (int t = 0; t < 10; ++t) {
        float wc = W_coord[t * 64 + lane];
        float wv = W_vel[t * 64 + lane];
#pragma unroll
        for (int d = 0; d < 3; ++d) {
            xh[d] += (xd[t][d] - xm[d]) * wc;
            vh[d] += vd[t][d] * wv;
        }
    }
#pragma unroll
    for (int d = 0; d < 3; ++d)
        ws[WS_XH + (node * 64 + lane) * 3 + d] = xh[d];
    // pair-packed fp16 coordT: channel c=lane (xh), 64+lane (vh)
    unsigned short* cth = (unsigned short*)(ws + WS_CTH) + (size_t)b * 192 * 256 * 2;
    int px = lane >> 1, sx = lane & 1;
#pragma unroll
    for (int d = 0; d < 3; ++d) {
        cth[((px * 3 + d) * 256 + n) * 2 + sx] =
            __builtin_bit_cast(unsigned short, (_Float16)xh[d]);
        cth[(((32 + px) * 3 + d) * 256 + n) * 2 + sx] =
            __builtin_bit_cast(unsigned short, (_Float16)vh[d]);
    }
    // ---- fused contrib1: bias_e/contrib_e from shared hh ----
    __syncthreads();
    int o = lane;
    float a1 = be1[o], a2 = 0.0f;
    for (int t = 0; t < 64; ++t) {
        float hv = shh[nd][t];
        a1 = fmaf(hv, We1[t * 64 + o], a1);
        a2 = fmaf(hv, We1[(64 + t) * 64 + o], a2);
    }
    ws[WS_BIASE + node * 64 + o] = a1;
    ws[WS_CONTRE + node * 64 + o] = a2;
}

// ---------------------------------------------------------------------------
// K3: prediction head + inverse DCT -> d_out[0 : 61440].
// ---------------------------------------------------------------------------
__global__ void k_xout(const float* __restrict__ W_pred, const float* __restrict__ ws,
                       float* __restrict__ out) {
    int nd = threadIdx.x >> 6, lane = threadIdx.x & 63;
    int node = blockIdx.x * 4 + nd;
    int b = node >> 8;
    __shared__ float sxp[4][60];
    float xm2[3];
#pragma unroll
    for (int d = 0; d < 3; ++d) xm2[d] = ws[WS_XM2 + b * 4 + d];
    if (lane < 60) {
        int o2 = lane / 3, d = lane % 3;
        const float* p = ws + WS_XH + node * 192;
        float acc = xm2[d];
        for (int c = 0; c < 64; ++c) acc += (p[c * 3 + d] - xm2[d]) * W_pred[c * 20 + o2];
        sxp[nd][lane] = acc;
    }
    __syncthreads();
    if (lane < 60) {
        int s = lane / 3, d = lane % 3;
        float w0 = sqrtf(0.05f), w1 = sqrtf(0.1f);
        float acc = ws[WS_XC + b * 4 + d];
#pragma unroll
        for (int t = 0; t < 20; ++t) {
            float coef = ((t == 0) ? w0 : w1) * cosf(PI_F * (s + 0.5f) * t * 0.05f);
            acc += coef * sxp[nd][t * 3 + d];
        }
        out[(node * 20 + s) * 3 + d] = acc;
    }
}

// ---------------------------------------------------------------------------
// K6: node_new MLP + category-head rank-1 terms (natural layout).
// ---------------------------------------------------------------------------
__global__ void k_nodes2(const float* __restrict__ Wn1, const float* __restrict__ bn1,
                         const float* __restrict__ Wn2, const float* __restrict__ bn2,
                         const float* __restrict__ Wk1, const float* __restrict__ bk1,
                         float* __restrict__ ws) {
    int nd = threadIdx.x >> 6;
    int o = threadIdx.x & 63;
    int node = blockIdx.x * 4 + nd;
    __shared__ float sg[4][64], snn[4][64];
    const float* hp = ws + WS_HH + node * 64;
    const float* ap = ws + WS_AGG + node * 64;
    float acc = bn1[o];
    for (int t = 0; t < 64; ++t) acc = fmaf(hp[t], Wn1[t * 64 + o], acc);
    for (int t = 0; t < 64; ++t) acc = fmaf(ap[t], Wn1[(64 + t) * 64 + o], acc);
    sg[nd][o] = silu(acc);
    __syncthreads();
    acc = bn2[o];
    for (int t = 0; t < 64; ++t) acc = fmaf(sg[nd][t], Wn2[t * 64 + o], acc);
    snn[nd][o] = silu(acc);
    __syncthreads();
    float bk = bk1[o], ck = 0.0f;
    for (int t = 0; t < 64; ++t) {
        float v = snn[nd][t];
        bk = fmaf(v, Wk1[t * 64 + o], bk);
        ck = fmaf(v, Wk1[(64 + t) * 64 + o], ck);
    }
    ws[WS_BIASK + node * 64 + o] = bk;
    ws[WS_CONTRK + node * 64 + o] = ck;
}

// ---------------------------------------------------------------------------
// K_pair<PASS>: MFMA pair pipeline, swapped operands (A=weights, B=activations,
// D cols = j = lane&15 throughout). Layer transitions fully in-register via
// pk2 + __shfl within lane groups {lr, lr+16, lr+32, lr+48}.
// Block: 512 threads = 8 waves; waves 0-3 -> i0, 4-7 -> i0+1; wave jw covers
// j in [64*jw, 64*jw+64), 16 j per mt iteration.
// amdgpu_waves_per_eu(4,4): measured best (60 VGPR, no spills).
// sched_barrier(0) stage fences: REQUIRED (R15). L2 half-split kept (R18's
// un-split was null; this is the exact R17-measured 67.7us configuration).
// ---------------------------------------------------------------------------
template<int PASS>
__global__ __attribute__((amdgpu_waves_per_eu(4, 4))) __launch_bounds__(512)
void k_pair(
    const float* __restrict__ bc1, const float* __restrict__ bc2,
    const float* __restrict__ bB,
    float* __restrict__ ws, float* __restrict__ out) {

    __shared__ __align__(16) unsigned short WL[28672];  // W1(8192) W2(8192) WA(8192) WB(4096)
    __shared__ __align__(16) unsigned sciu[2][192];     // i-rows, fp16 pair-packed
    __shared__ __align__(16) float sb1[64];
    __shared__ __align__(16) float sb2[128];
    __shared__ __align__(16) float sbB[64];
    __shared__ __align__(16) float sbias[2][64];
    __shared__ float sred[8][64];

    const int tid = threadIdx.x;
    const int b = blockIdx.y;
    const int i0 = blockIdx.x * 2;
    const unsigned* cTu = (const unsigned*)(ws + WS_CTH) + (size_t)b * 192 * 256;
    const unsigned short* wsu = (const unsigned short*)(ws + WS_WF);

    // ---- stage fragment-major weights (coalesced uint4 copies) ----
    {
        const uint4* s0 = (const uint4*)(wsu + OW1);            // W1+W2: 2048 u4
        uint4* d0 = (uint4*)(&WL[0]);
        for (int t = tid; t < 2048; t += 512) d0[t] = s0[t];
        const uint4* s1 = (const uint4*)(wsu + (PASS ? OWAK : OWAE));
        uint4* d1 = (uint4*)(&WL[16384]);
        for (int t = tid; t < 1024; t += 512) d1[t] = s1[t];
        const uint4* s2 = (const uint4*)(wsu + (PASS ? OWBK : OWBE));
        uint4* d2 = (uint4*)(&WL[24576]);
        int nb = PASS ? 128 : 512;
        for (int t = tid; t < nb; t += 512) d2[t] = s2[t];
    }
    for (int idx = tid; idx < 384; idx += 512) {
        int ii2 = idx / 192, q = idx % 192;
        sciu[ii2][q] = cTu[q * 256 + (i0 + ii2)];
    }
    if (tid < 64)  sb1[tid] = bc1[tid];
    if (tid < 128) sb2[tid] = bc2[tid];
    if (tid < 64)  sbB[tid] = (PASS == 0) ? bB[tid] : (tid < 4 ? bB[tid] : 0.0f);
    {
        const float* bias = ws + ((PASS == 0) ? WS_BIASE : WS_BIASK);
        if (tid < 128) {
            int ii = tid >> 6, o = tid & 63;
            sbias[ii][o] = bias[(b * 256 + i0 + ii) * 64 + o];
        }
    }
    __syncthreads();

    const int w = tid >> 6, lane = tid & 63;
    const int lr = lane & 15, lg = lane >> 4;
    const int ii = w >> 2, jw = w & 3;
    const int i = i0 + ii;
    const float* contrib = ws + ((PASS == 0) ? WS_CONTRE : WS_CONTRK) + b * 256 * 64;

    const int S0 = ((lg & 1) << 5) + lr;
    const int S1 = S0 + 16;
    const bool hi = (lg >> 1) != 0;

    const unsigned short* W1L = WL;
    const unsigned short* W2L = WL + 8192;
    const unsigned short* WAL = WL + 16384;
    const unsigned short* WBL = WL + 24576;

    // hoist mt-invariant i-row channel pairs (16 pairs x 3 dims) to registers
    unsigned cia[48];
#pragma unroll
    for (int kt = 0; kt < 4; ++kt)
#pragma unroll
        for (int q = 0; q < 4; ++q) {
            int p3 = (16 * kt + 4 * lg + q) * 3;
#pragma unroll
            for (int d = 0; d < 3; ++d)
                cia[(kt * 4 + q) * 3 + d] = sciu[ii][p3 + d];
        }

    float pacc[16];
#pragma unroll
    for (int t = 0; t < 16; ++t) pacc[t] = 0.0f;

#pragma unroll 1
    for (int mt = 0; mt < 4; ++mt) {
        const int jbase = 64 * jw + 16 * mt;
        const int j = jbase + lr;

        // ---- dist B-fragments, packed fp16: dword q of as[kt] = channel pair
        // p = 16kt+4lg+q = channels {2p, 2p+1} for column j.
        f16x8 as[4];
#pragma unroll
        for (int kt = 0; kt < 4; ++kt) {
            union { f16x8 v; unsigned u[4]; } r;
#pragma unroll
            for (int q = 0; q < 4; ++q) {
                int p3 = (16 * kt + 4 * lg + q) * 3;
                int ci = (kt * 4 + q) * 3;
                f16x2 d0 = __builtin_bit_cast(f16x2, cia[ci + 0]) -
                           __builtin_bit_cast(f16x2, cTu[(p3 + 0) * 256 + j]);
                f16x2 d1 = __builtin_bit_cast(f16x2, cia[ci + 1]) -
                           __builtin_bit_cast(f16x2, cTu[(p3 + 1) * 256 + j]);
                f16x2 d2 = __builtin_bit_cast(f16x2, cia[ci + 2]) -
                           __builtin_bit_cast(f16x2, cTu[(p3 + 2) * 256 + j]);
                f16x2 s = d0 * d0 + d1 * d1 + d2 * d2;
                r.u[q] = pk2(sqrtf((float)s[0]), sqrtf((float)s[1]));
            }
            as[kt] = r.v;
        }
        __builtin_amdgcn_sched_barrier(0);

        // ---- L1: t1 = silu(Wc1 . dist), rows o, cols j.  K=128 ----
        unsigned Q1[8];
#pragma unroll
        for (int nt = 0; nt < 4; ++nt) {
            float4 bv = *(const float4*)&sb1[16 * nt + 4 * lg];
            f32x4 d = {bv.x, bv.y, bv.z, bv.w};
#pragma unroll
            for (int kt = 0; kt < 4; ++kt) {
                f16x8 af = *(const f16x8*)&W1L[((nt * 4 + kt) * 64 + lane) * 8];
                d = __builtin_amdgcn_mfma_f32_16x16x32_f16(af, as[kt], d, 0, 0, 0);
            }
            Q1[nt * 2 + 0] = pk2(silu(d[0]), silu(d[1]));
            Q1[nt * 2 + 1] = pk2(silu(d[2]), silu(d[3]));
        }
        f16x8 a2[2];
        xfrag<2>(Q1, S0, S1, hi, a2);
        __builtin_amdgcn_sched_barrier(0);

        // ---- L2: cd = silu(Wc2 . t1), rows cc (128), cols j.  K=64 ----
        // Two 64-row halves; each half's Q2 consumed by xfrag immediately.
        f16x8 a3[4];
#pragma unroll
        for (int half = 0; half < 2; ++half) {
            unsigned Q2[8];
#pragma unroll
            for (int nc = 0; nc < 4; ++nc) {
                int ntc = half * 4 + nc;
                float4 bv = *(const float4*)&sb2[16 * ntc + 4 * lg];
                f32x4 d = {bv.x, bv.y, bv.z, bv.w};
#pragma unroll
                for (int kt = 0; kt < 2; ++kt) {
                    f16x8 af = *(const f16x8*)&W2L[((ntc * 2 + kt) * 64 + lane) * 8];
                    d = __builtin_amdgcn_mfma_f32_16x16x32_f16(af, a2[kt], d, 0, 0, 0);
                }
                Q2[nc * 2 + 0] = pk2(silu(d[0]), silu(d[1]));
                Q2[nc * 2 + 1] = pk2(silu(d[2]), silu(d[3]));
            }
            xfrag<2>(Q2, S0, S1, hi, &a3[half * 2]);
            __builtin_amdgcn_sched_barrier(0);
        }

        // ---- L3: e1 = silu(bias + contrib_j + WA . cd), rows o, cols j. K=128 ----
        unsigned Q3[8];
#pragma unroll
        for (int nt = 0; nt < 4; ++nt) {
            float4 bv = *(const float4*)&sbias[ii][16 * nt + 4 * lg];
            float4 ce = *(const float4*)&contrib[j * 64 + 16 * nt + 4 * lg];
            f32x4 d = {bv.x + ce.x, bv.y + ce.y, bv.z + ce.z, bv.w + ce.w};
#pragma unroll
            for (int kt = 0; kt < 4; ++kt) {
                f16x8 af = *(const f16x8*)&WAL[((nt * 4 + kt) * 64 + lane) * 8];
                d = __builtin_amdgcn_mfma_f32_16x16x32_f16(af, a3[kt], d, 0, 0, 0);
            }
            Q3[nt * 2 + 0] = pk2(silu(d[0]), silu(d[1]));
            Q3[nt * 2 + 1] = pk2(silu(d[2]), silu(d[3]));
        }
        f16x8 a4[2];
        xfrag<2>(Q3, S0, S1, hi, a4);
        __builtin_amdgcn_sched_barrier(0);

        // ---- L4 ----
        if (PASS == 0) {
            // edge = silu(We2 . e1), rows o2, cols j; mask j==i; accumulate col-sums
#pragma unroll
            for (int nt = 0; nt < 4; ++nt) {
                float4 bv = *(const float4*)&sbB[16 * nt + 4 * lg];
                f32x4 d = {bv.x, bv.y, bv.z, bv.w};
#pragma unroll
                for (int kt = 0; kt < 2; ++kt) {
                    f16x8 af = *(const f16x8*)&WBL[((nt * 2 + kt) * 64 + lane) * 8];
                    d = __builtin_amdgcn_mfma_f32_16x16x32_f16(af, a4[kt], d, 0, 0, 0);
                }
                float m = (j == i) ? 0.0f : 1.0f;
#pragma unroll
                for (int r = 0; r < 4; ++r)
                    pacc[nt * 4 + r] += m * silu(d[r]);
            }
        } else {
            // logits rows = cat (0..3 real, rest zero-weight), cols j
            f32x4 d;
            if (lg == 0) {
                float4 bv = *(const float4*)&sbB[0];
                d = {bv.x, bv.y, bv.z, bv.w};
            } else {
                d = {0.0f, 0.0f, 0.0f, 0.0f};
            }
#pragma unroll
            for (int kt = 0; kt < 2; ++kt) {
                f16x8 af = *(const f16x8*)&WBL[(kt * 64 + lane) * 8];
                d = __builtin_amdgcn_mfma_f32_16x16x32_f16(af, a4[kt], d, 0, 0, 0);
            }
            if (lg == 0) {
                float l0 = silu(d[0]), l1 = silu(d[1]), l2 = silu(d[2]), l3 = silu(d[3]);
                float mx = fmaxf(fmaxf(l0, l1), fmaxf(l2, l3));
                float e0 = __expf(l0 - mx), e1 = __expf(l1 - mx);
                float e2 = __expf(l2 - mx), e3 = __expf(l3 - mx);
                float inv = __builtin_amdgcn_rcpf(e0 + e1 + e2 + e3);
                float4 r = make_float4(e0 * inv, e1 * inv, e2 * inv, e3 * inv);
                *(float4*)&out[61440 + (((b * 256 + i) * 256 + j) << 2)] = r;
            }
        }
        __builtin_amdgcn_sched_barrier(0);
    }

    if (PASS == 0) {
        // reduce over the 16 j-lanes (lr) of each row group
#pragma unroll
        for (int t = 0; t < 16; ++t) {
            pacc[t] += __shfl_xor(pacc[t], 1, 64);
            pacc[t] += __shfl_xor(pacc[t], 2, 64);
            pacc[t] += __shfl_xor(pacc[t], 4, 64);
            pacc[t] += __shfl_xor(pacc[t], 8, 64);
        }
        if (lr == 0) {
#pragma unroll
            for (int nt = 0; nt < 4; ++nt)
#pragma unroll
                for (int r = 0; r < 4; ++r)
                    sred[w][16 * nt + 4 * lg + r] = pacc[nt * 4 + r];
        }
        __syncthreads();
        if (tid < 128) {
            int iw = tid >> 6, o = tid & 63;
            float s = sred[iw * 4 + 0][o] + sred[iw * 4 + 1][o] +
                      sred[iw * 4 + 2][o] + sred[iw * 4 + 3][o];
            ws[WS_AGG + (b * 256 + i0 + iw) * 64 + o] = s;
        }
    }
}

// ---------------------------------------------------------------------------
extern "C" void kernel_launch(void* const* d_in, const int* in_sizes, int n_in,
                              void* d_out, int out_size, void* d_ws, size_t ws_size,
                              hipStream_t stream) {
    (void)in_sizes; (void)n_in; (void)out_size; (void)ws_size;
    const float* h      = (const float*)d_in[0];
    const float* x      = (const float*)d_in[1];
    const float* vel    = (const float*)d_in[2];
    const float* W_emb  = (const float*)d_in[3];
    const float* b_emb  = (const float*)d_in[4];
    const float* W_emb2 = (const float*)d_in[5];
    const float* b_emb2 = (const float*)d_in[6];
    const float* W_coord= (const float*)d_in[7];
    const float* W_vel  = (const float*)d_in[8];
    const float* W_pred = (const float*)d_in[9];
    const float* Wc1    = (const float*)d_in[10];
    const float* bc1    = (const float*)d_in[11];
    const float* Wc2    = (const float*)d_in[12];
    const float* bc2    = (const float*)d_in[13];
    const float* We1    = (const float*)d_in[14];
    const float* be1    = (const float*)d_in[15];
    const float* We2    = (const float*)d_in[16];
    const float* be2    = (const float*)d_in[17];
    const float* Wn1    = (const float*)d_in[18];
    const float* bn1    = (const float*)d_in[19];
    const float* Wn2    = (const float*)d_in[20];
    const float* bn2    = (const float*)d_in[21];
    const float* Wk1    = (const float*)d_in[22];
    const float* bk1    = (const float*)d_in[23];
    const float* Wk2    = (const float*)d_in[24];
    const float* bk2    = (const float*)d_in[25];
    float* ws  = (float*)d_ws;
    float* out = (float*)d_out;

    k_prepstats<<<152, 256, 0, stream>>>(Wc1, Wc2, We1, Wk1, We2, Wk2, x, W_coord, ws);
    k_nodes<<<256, 256, 0, stream>>>(x, vel, h, W_emb, b_emb, W_emb2, b_emb2,
                                     W_coord, W_vel, We1, be1, ws);
    k_xout<<<256, 256, 0, stream>>>(W_pred, ws, out);
    k_pair<0><<<dim3(128, 4), 512, 0, stream>>>(bc1, bc2, be2, ws, out);
    k_nodes2<<<256, 256, 0, stream>>>(Wn1, bn1, Wn2, bn2, Wk1, bk1, ws);
    k_pair<1><<<dim3(128, 4), 512, 0, stream>>>(bc1, bc2, bk2, ws, out);
}